// Round 4
// baseline (770.044 us; speedup 1.0000x reference)
//
#include <hip/hip_runtime.h>
#include <stdint.h>

// ---------------------------------------------------------------------------
// BailingMoE block: T=1024, H=1024, E=16, top-4, I=512 routed, Is=1024 shared
// R4: barrier-free GEMM phases. No LDS staging: every lane loads its own MFMA
// fragments global->VGPR (16 fully-used 64B lines per instr), 3-step-deep
// register pipeline, zero __syncthreads in the K-loop. Small-GEMM regime
// (~192 blocks, 1 wave/SIMD) is latency-bound; ILP via vmcnt depth replaces
// the TLP we don't have.
// ---------------------------------------------------------------------------

typedef __attribute__((ext_vector_type(8))) unsigned short ushort8;
typedef __attribute__((ext_vector_type(4))) float f32x4;
typedef __attribute__((ext_vector_type(8))) __bf16 bf16x8;

#define T_TOK 1024
#define HID   1024
#define NEXP  16
#define TOPK  4
#define MINTER 512
#define SINTER 1024

constexpr size_t OFF_COUNTS = 0;                               // 16 ints
constexpr size_t OFF_LIST   = 1024;                            // 16*1024 ints
constexpr size_t OFF_WT     = OFF_LIST  + 65536;               // 16*1024 floats
constexpr size_t OFF_TIDX   = OFF_WT    + 65536;               // 4096 ints
constexpr size_t OFF_XB     = OFF_TIDX  + 65536;               // bf16 1024x1024
constexpr size_t OFF_HS     = OFF_XB    + 2097152;             // bf16 1024x1024
constexpr size_t OFF_HR     = OFF_HS    + 2097152;             // bf16 4096x512 compact
constexpr size_t OFF_WGT    = OFF_HR    + 4194304;             // bf16 16x512x1024
constexpr size_t OFF_WUT    = OFF_WGT   + 16777216;            // bf16 16x512x1024
constexpr size_t OFF_WDT    = OFF_WUT   + 16777216;            // bf16 16x1024x512
constexpr size_t OFF_WSGUT  = OFF_WDT   + 16777216;            // bf16 2048x1024
constexpr size_t OFF_WSDT   = OFF_WSGUT + 4194304;             // bf16 1024x1024
constexpr size_t OFF_ROUT   = OFF_WGT;   // bf16 4096x1024 overlay (WgT dead in phase2)

__device__ __forceinline__ unsigned short f2bf(float f) {
  union { float f; uint32_t u; } v; v.f = f;
  uint32_t r = (v.u + 0x7FFFu + ((v.u >> 16) & 1u)) >> 16;
  return (unsigned short)r;
}
__device__ __forceinline__ float bfu2f(uint32_t u) {
  union { uint32_t u; float f; } v; v.u = u << 16; return v.f;
}
__device__ __forceinline__ bf16x8 as_bf16x8(ushort8 s) {
  union { ushort8 s; bf16x8 b; } u; u.s = s; return u.b;
}
__device__ __forceinline__ float silu(float g) { return g / (1.f + __expf(-g)); }

// -------------------------- init: zero expert counts -----------------------
__global__ void init_kernel(int* counts) {
  if (threadIdx.x < NEXP) counts[threadIdx.x] = 0;
}

// ------------- router (fp32, one wave/token) + fused x->bf16 write ---------
__global__ __launch_bounds__(64) void router_kernel(
    const float* __restrict__ x, const float* __restrict__ rw,
    int* counts, int* list, float* wt, int* tIdx,
    unsigned short* __restrict__ Xb) {
  const int t = blockIdx.x, l = threadIdx.x;
  float xv[16];
#pragma unroll
  for (int j = 0; j < 16; j++) xv[j] = x[t * HID + j * 64 + l];
#pragma unroll
  for (int j = 0; j < 16; j++) Xb[t * HID + j * 64 + l] = f2bf(xv[j]);
  float p[NEXP];
#pragma unroll
  for (int e = 0; e < NEXP; e++) {
    float s = 0.f;
#pragma unroll
    for (int j = 0; j < 16; j++) s += xv[j] * rw[e * HID + j * 64 + l];
#pragma unroll
    for (int off = 32; off > 0; off >>= 1) s += __shfl_xor(s, off);
    p[e] = s;
  }
  float mx = p[0];
#pragma unroll
  for (int e = 1; e < NEXP; e++) mx = fmaxf(mx, p[e]);
  int idx[TOPK]; float w4[TOPK]; float wsum = 0.f; unsigned used = 0u;
#pragma unroll
  for (int k = 0; k < TOPK; k++) {
    float bv = -1e30f; int bi = 0;
#pragma unroll
    for (int e = 0; e < NEXP; e++)
      if (!((used >> e) & 1u) && p[e] > bv) { bv = p[e]; bi = e; }
    used |= 1u << bi;
    idx[k] = bi;
    w4[k] = __expf(p[bi] - mx);
    wsum += w4[k];
  }
  const float inv = 1.f / wsum;  // softmax denom cancels under top-k renorm
  if (l < TOPK) {
    const int e = idx[l];
    const int pos = atomicAdd(&counts[e], 1);
    list[e * 1024 + pos] = t;
    wt[e * 1024 + pos]   = w4[l] * inv;
    tIdx[t * TOPK + l]   = (e << 10) | pos;
  }
}

// ---------------- one dispatch: all 5 weight transposes (fp32->bf16) -------
__global__ __launch_bounds__(256) void transpose_all_kernel(
    const float* __restrict__ Wg, const float* __restrict__ Wu,
    const float* __restrict__ Wd, const float* __restrict__ Wsgu,
    const float* __restrict__ Wsd,
    unsigned short* __restrict__ WgT, unsigned short* __restrict__ WuT,
    unsigned short* __restrict__ WdT, unsigned short* __restrict__ WsguT,
    unsigned short* __restrict__ WsdT) {
  const int bid = blockIdx.x;
  const float* src; unsigned short* dst; int R, C, tx, ty; size_t bo;
  if (bid < 4096) {                    // Wg/Wu: [16][1024][512]
    const int which = bid >> 11, loc = bid & 2047;
    const int b = loc >> 7, t8 = loc & 127;
    src = which ? Wu : Wg; dst = which ? WuT : WgT;
    R = 1024; C = 512; bo = (size_t)b * R * C;
    tx = t8 & 7; ty = t8 >> 3;
  } else if (bid < 6144) {             // Wd: [16][512][1024]
    const int loc = bid - 4096, b = loc >> 7, t8 = loc & 127;
    src = Wd; dst = WdT; R = 512; C = 1024; bo = (size_t)b * R * C;
    tx = t8 & 15; ty = t8 >> 4;
  } else if (bid < 6656) {             // Wsgu: [1024][2048]
    const int loc = bid - 6144;
    src = Wsgu; dst = WsguT; R = 1024; C = 2048; bo = 0;
    tx = loc & 31; ty = loc >> 5;
  } else {                             // Wsd: [1024][1024]
    const int loc = bid - 6656;
    src = Wsd; dst = WsdT; R = 1024; C = 1024; bo = 0;
    tx = loc & 15; ty = loc >> 4;
  }
  __shared__ float tile[64][65];
  const int c0 = tx * 64, r0 = ty * 64, t = threadIdx.x;
  {
    const int r = t >> 4, c4 = (t & 15) * 4;
#pragma unroll
    for (int p = 0; p < 4; p++) {
      const int rr = p * 16 + r;
      const float4 v = *(const float4*)(src + bo + (size_t)(r0 + rr) * C + c0 + c4);
      tile[rr][c4 + 0] = v.x; tile[rr][c4 + 1] = v.y;
      tile[rr][c4 + 2] = v.z; tile[rr][c4 + 3] = v.w;
    }
  }
  __syncthreads();
  {
    const int c = t >> 2, rb = (t & 3) * 16;
#pragma unroll
    for (int s = 0; s < 4; s++) {
      const int rr = rb + 4 * s;
      union { unsigned short u[4]; uint2 v; } pk;
#pragma unroll
      for (int i = 0; i < 4; i++) pk.u[i] = f2bf(tile[rr + i][c]);
      *(uint2*)(dst + bo + (size_t)(c0 + c) * R + r0 + rr) = pk.v;
    }
  }
}

// ---------------------------------------------------------------------------
// Phase 1: gate/up, barrier-free. Block 256 thr = 4 waves (2m x 2n), block
// tile 128 rows x 128 cols (G and U). Wave tile 64 x 64(G)+64(U).
// Every lane loads its own A/B fragments (dwordx4 = one 16x32 frag slice).
// 3-deep register pipeline; no LDS, no __syncthreads.
// ---------------------------------------------------------------------------
__global__ __launch_bounds__(256, 1) void phase1_kernel(
    const unsigned short* __restrict__ Xb,
    const unsigned short* __restrict__ WgT,   // [16][512][1024]
    const unsigned short* __restrict__ WuT,   // [16][512][1024]
    const unsigned short* __restrict__ WsguT, // [2048][1024]
    const int* __restrict__ counts, const int* __restrict__ list,
    const float* __restrict__ wt,
    unsigned short* __restrict__ Hr,          // [4096][512] compact
    unsigned short* __restrict__ Hs) {        // [1024][1024]
  const int z = blockIdx.z, x = blockIdx.x, y = blockIdx.y;
  const bool routed = (z < NEXP);
  int cnt = 0, base = 0;
  if (routed) {
    if (x >= 4) return;                       // routed: 4 x-tiles of 128 I-cols
    cnt = counts[z];
    if (y * 128 >= cnt) return;
#pragma unroll
    for (int i = 0; i < NEXP; i++) base += (i < z) ? counts[i] : 0;
  }
  const int tid = threadIdx.x, w = tid >> 6, l = tid & 63;
  const int wm = w >> 1, wn = w & 1, m0 = y * 128;
  const int kq = (l >> 4) * 8;                // k-offset of this lane's frag

  // per-lane fragment base pointers
  const unsigned short* aP[4];
#pragma unroll
  for (int i = 0; i < 4; i++) {
    const int row = m0 + wm * 64 + 16 * i + (l & 15);
    if (routed) aP[i] = Xb + (size_t)list[z * 1024 + min(row, cnt - 1)] * HID + kq;
    else        aP[i] = Xb + (size_t)row * HID + kq;
  }
  const unsigned short *gP[4], *uP[4];
#pragma unroll
  for (int j = 0; j < 4; j++) {
    const int n = x * 128 + wn * 64 + 16 * j + (l & 15);
    if (routed) {
      gP[j] = WgT + ((size_t)z * MINTER + n) * HID + kq;
      uP[j] = WuT + ((size_t)z * MINTER + n) * HID + kq;
    } else {
      gP[j] = WsguT + (size_t)n * HID + kq;
      uP[j] = WsguT + (size_t)(SINTER + n) * HID + kq;
    }
  }

  f32x4 accG[4][4], accU[4][4];
#pragma unroll
  for (int i = 0; i < 4; i++)
#pragma unroll
    for (int j = 0; j < 4; j++) {
      accG[i][j] = (f32x4){0.f, 0.f, 0.f, 0.f};
      accU[i][j] = (f32x4){0.f, 0.f, 0.f, 0.f};
    }

  // 3-deep register pipeline over K (steps = HID/32 = 32)
  ushort8 Af[3][4], Gf[3][4], Uf[3][4];
#define P1_LD(st, k0)                                                   \
  {                                                                     \
    _Pragma("unroll") for (int i = 0; i < 4; i++)                       \
        Af[st][i] = *(const ushort8*)(aP[i] + (k0));                    \
    _Pragma("unroll") for (int j = 0; j < 4; j++) {                     \
      Gf[st][j] = *(const ushort8*)(gP[j] + (k0));                      \
      Uf[st][j] = *(const ushort8*)(uP[j] + (k0));                      \
    }                                                                   \
  }
  P1_LD(0, 0) P1_LD(1, 32) P1_LD(2, 64)
  const int steps = HID / 32;
#pragma unroll 1
  for (int s = 0; s < steps; s++) {
    const int cur = s % 3;
#pragma unroll
    for (int j = 0; j < 4; j++) {
      const bf16x8 gf = as_bf16x8(Gf[cur][j]);
      const bf16x8 uf = as_bf16x8(Uf[cur][j]);
#pragma unroll
      for (int i = 0; i < 4; i++) {
        const bf16x8 af = as_bf16x8(Af[cur][i]);
        accG[i][j] = __builtin_amdgcn_mfma_f32_16x16x32_bf16(af, gf, accG[i][j], 0, 0, 0);
        accU[i][j] = __builtin_amdgcn_mfma_f32_16x16x32_bf16(af, uf, accU[i][j], 0, 0, 0);
      }
    }
    if (s + 3 < steps) P1_LD(cur, (s + 3) * 32)
  }
#undef P1_LD

  // epilogue: C/D map col=lane&15, row=(lane>>4)*4+reg
#pragma unroll
  for (int i = 0; i < 4; i++)
#pragma unroll
    for (int r = 0; r < 4; r++) {
      const int row = wm * 64 + 16 * i + (l >> 4) * 4 + r;
      const int grow = m0 + row;
      if (routed) {
        if (grow < cnt) {
          const float wrow = wt[z * 1024 + grow];
#pragma unroll
          for (int j = 0; j < 4; j++) {
            const int col = x * 128 + wn * 64 + 16 * j + (l & 15);
            const float h = silu(accG[i][j][r]) * accU[i][j][r] * wrow;
            Hr[(size_t)(base + grow) * MINTER + col] = f2bf(h);
          }
        }
      } else {
#pragma unroll
        for (int j = 0; j < 4; j++) {
          const int col = x * 128 + wn * 64 + 16 * j + (l & 15);
          const float h = silu(accG[i][j][r]) * accU[i][j][r];
          Hs[(size_t)grow * SINTER + col] = f2bf(h);
        }
      }
    }
}

// ---------------------------------------------------------------------------
// Phase 2: down-proj, barrier-free. Block 256 thr = 4 waves (2x2), block tile
// 128 x 256; wave tile 64 x 128. Routed (z<16): K=512 -> bf16 Rout; shared
// (z==16): K=1024 -> fp32 out.
// ---------------------------------------------------------------------------
__global__ __launch_bounds__(256, 1) void phase2_kernel(
    const unsigned short* __restrict__ Hr, const unsigned short* __restrict__ Hs,
    const unsigned short* __restrict__ WdT,  // [16][1024][512]
    const unsigned short* __restrict__ WsdT, // [1024][1024]
    const int* __restrict__ counts,
    unsigned short* __restrict__ Rout,       // [4096][1024] bf16 compact
    float* __restrict__ out) {               // [1024][1024]
  const int z = blockIdx.z, x = blockIdx.x, y = blockIdx.y;
  const bool routed = (z < NEXP);
  int cnt = 0, base = 0, kdim;
  if (routed) {
    cnt = counts[z];
    if (y * 128 >= cnt) return;
#pragma unroll
    for (int i = 0; i < NEXP; i++) base += (i < z) ? counts[i] : 0;
    kdim = MINTER;
  } else {
    kdim = SINTER;
  }
  const int tid = threadIdx.x, w = tid >> 6, l = tid & 63;
  const int wm = w >> 1, wn = w & 1, m0 = y * 128;
  const int kq = (l >> 4) * 8;

  const unsigned short* aP[4];
#pragma unroll
  for (int i = 0; i < 4; i++) {
    const int row = m0 + wm * 64 + 16 * i + (l & 15);
    if (routed) aP[i] = Hr + (size_t)(base + min(row, cnt - 1)) * MINTER + kq;
    else        aP[i] = Hs + (size_t)row * SINTER + kq;
  }
  const unsigned short* bP[8];
#pragma unroll
  for (int j = 0; j < 8; j++) {
    const int n = x * 256 + wn * 128 + 16 * j + (l & 15);
    bP[j] = routed ? (WdT + ((size_t)z * HID + n) * MINTER + kq)
                   : (WsdT + (size_t)n * SINTER + kq);
  }

  f32x4 acc[4][8];
#pragma unroll
  for (int i = 0; i < 4; i++)
#pragma unroll
    for (int j = 0; j < 8; j++) acc[i][j] = (f32x4){0.f, 0.f, 0.f, 0.f};

  ushort8 Af[3][4], Bf[3][8];
#define P2_LD(st, k0)                                                   \
  {                                                                     \
    _Pragma("unroll") for (int i = 0; i < 4; i++)                       \
        Af[st][i] = *(const ushort8*)(aP[i] + (k0));                    \
    _Pragma("unroll") for (int j = 0; j < 8; j++)                       \
        Bf[st][j] = *(const ushort8*)(bP[j] + (k0));                    \
  }
  P2_LD(0, 0) P2_LD(1, 32) P2_LD(2, 64)
  const int steps = kdim / 32;
#pragma unroll 1
  for (int s = 0; s < steps; s++) {
    const int cur = s % 3;
#pragma unroll
    for (int j = 0; j < 8; j++) {
      const bf16x8 bfv = as_bf16x8(Bf[cur][j]);
#pragma unroll
      for (int i = 0; i < 4; i++) {
        const bf16x8 af = as_bf16x8(Af[cur][i]);
        acc[i][j] = __builtin_amdgcn_mfma_f32_16x16x32_bf16(af, bfv, acc[i][j], 0, 0, 0);
      }
    }
    if (s + 3 < steps) P2_LD(cur, (s + 3) * 32)
  }
#undef P2_LD

#pragma unroll
  for (int i = 0; i < 4; i++)
#pragma unroll
    for (int r = 0; r < 4; r++) {
      const int row = wm * 64 + 16 * i + (l >> 4) * 4 + r;
      const int grow = m0 + row;
      if (routed) {
        if (grow < cnt) {
#pragma unroll
          for (int j = 0; j < 8; j++) {
            const int col = x * 256 + wn * 128 + 16 * j + (l & 15);
            Rout[(size_t)(base + grow) * HID + col] = f2bf(acc[i][j][r]);
          }
        }
      } else {
#pragma unroll
        for (int j = 0; j < 8; j++) {
          const int col = x * 256 + wn * 128 + 16 * j + (l & 15);
          out[(size_t)grow * HID + col] = acc[i][j][r];
        }
      }
    }
}

// ------------- combine: out[t] += sum_k Rout[base[e_k]+pos_k] (bf16) -------
__global__ __launch_bounds__(256) void combine_kernel(
    const unsigned short* __restrict__ Rout, const int* __restrict__ counts,
    const int* __restrict__ tIdx, float* __restrict__ out) {
  __shared__ int sb[NEXP];
  if (threadIdx.x == 0) {
    int s = 0;
#pragma unroll
    for (int e = 0; e < NEXP; e++) { sb[e] = s; s += counts[e]; }
  }
  __syncthreads();
  const int t = blockIdx.x, c4 = threadIdx.x * 4;
  float4 o = *(const float4*)(out + (size_t)t * HID + c4);
#pragma unroll
  for (int k = 0; k < TOPK; k++) {
    const int v = tIdx[t * TOPK + k];
    const int row = sb[v >> 10] + (v & 1023);
    const uint2 rv = *(const uint2*)(Rout + (size_t)row * HID + c4);
    o.x += bfu2f(rv.x & 0xffffu); o.y += bfu2f(rv.x >> 16);
    o.z += bfu2f(rv.y & 0xffffu); o.w += bfu2f(rv.y >> 16);
  }
  *(float4*)(out + (size_t)t * HID + c4) = o;
}

// ---------------------------------------------------------------------------
extern "C" void kernel_launch(void* const* d_in, const int* in_sizes, int n_in,
                              void* d_out, int out_size, void* d_ws, size_t ws_size,
                              hipStream_t stream) {
  const float* x      = (const float*)d_in[0];
  const float* rw     = (const float*)d_in[1];
  const float* w_gate = (const float*)d_in[2];
  const float* w_up   = (const float*)d_in[3];
  const float* w_down = (const float*)d_in[4];
  const float* ws_gu  = (const float*)d_in[5];
  const float* ws_dn  = (const float*)d_in[6];
  float* out = (float*)d_out;
  char* ws = (char*)d_ws;

  int*   counts = (int*)  (ws + OFF_COUNTS);
  int*   list   = (int*)  (ws + OFF_LIST);
  float* wtbuf  = (float*)(ws + OFF_WT);
  int*   tIdx   = (int*)  (ws + OFF_TIDX);
  unsigned short* Xb    = (unsigned short*)(ws + OFF_XB);
  unsigned short* Hs    = (unsigned short*)(ws + OFF_HS);
  unsigned short* Hr    = (unsigned short*)(ws + OFF_HR);
  unsigned short* WgT   = (unsigned short*)(ws + OFF_WGT);
  unsigned short* WuT   = (unsigned short*)(ws + OFF_WUT);
  unsigned short* WdT   = (unsigned short*)(ws + OFF_WDT);
  unsigned short* WsguT = (unsigned short*)(ws + OFF_WSGUT);
  unsigned short* WsdT  = (unsigned short*)(ws + OFF_WSDT);
  unsigned short* Rout  = (unsigned short*)(ws + OFF_ROUT);

  init_kernel<<<1, 64, 0, stream>>>(counts);
  router_kernel<<<T_TOK, 64, 0, stream>>>(x, rw, counts, list, wtbuf, tIdx, Xb);
  transpose_all_kernel<<<6912, 256, 0, stream>>>(
      w_gate, w_up, w_down, ws_gu, ws_dn, WgT, WuT, WdT, WsguT, WsdT);
  phase1_kernel<<<dim3(8, 8, 17), 256, 0, stream>>>(
      Xb, WgT, WuT, WsguT, counts, list, wtbuf, Hr, Hs);
  phase2_kernel<<<dim3(4, 8, 17), 256, 0, stream>>>(
      Hr, Hs, WdT, WsdT, counts, Rout, out);
  combine_kernel<<<T_TOK, 256, 0, stream>>>(Rout, counts, tIdx, out);
  (void)in_sizes; (void)n_in; (void)out_size; (void)ws_size;
}

// Round 5
// 281.427 us; speedup vs baseline: 2.7362x; 2.7362x over previous
//
#include <hip/hip_runtime.h>
#include <stdint.h>

// ---------------------------------------------------------------------------
// BailingMoE block: T=1024, H=1024, E=16, top-4, I=512 routed, Is=1024 shared
// R5: LDS-staged GEMM phases with a 3-buffer glds16 pipeline and raw-asm
// barriers (s_waitcnt vmcnt(12)+s_barrier) so prefetched loads stay in flight
// across barriers (AITER-style). 64B LDS rows -> conflict-free b128 frags.
// Transpose pass: coalesced 16B stores.
// ---------------------------------------------------------------------------

typedef __attribute__((ext_vector_type(8))) unsigned short ushort8;
typedef __attribute__((ext_vector_type(4))) float f32x4;
typedef __attribute__((ext_vector_type(8))) __bf16 bf16x8;

#define T_TOK 1024
#define HID   1024
#define NEXP  16
#define TOPK  4
#define MINTER 512
#define SINTER 1024

constexpr size_t OFF_COUNTS = 0;                               // 16 ints
constexpr size_t OFF_LIST   = 1024;                            // 16*1024 ints
constexpr size_t OFF_WT     = OFF_LIST  + 65536;               // 16*1024 floats
constexpr size_t OFF_TIDX   = OFF_WT    + 65536;               // 4096 ints
constexpr size_t OFF_XB     = OFF_TIDX  + 65536;               // bf16 1024x1024
constexpr size_t OFF_HS     = OFF_XB    + 2097152;             // bf16 1024x1024
constexpr size_t OFF_HR     = OFF_HS    + 2097152;             // bf16 4096x512 compact
constexpr size_t OFF_WGT    = OFF_HR    + 4194304;             // bf16 16x512x1024
constexpr size_t OFF_WUT    = OFF_WGT   + 16777216;            // bf16 16x512x1024
constexpr size_t OFF_WDT    = OFF_WUT   + 16777216;            // bf16 16x1024x512
constexpr size_t OFF_WSGUT  = OFF_WDT   + 16777216;            // bf16 2048x1024
constexpr size_t OFF_WSDT   = OFF_WSGUT + 4194304;             // bf16 1024x1024
constexpr size_t OFF_ROUT   = OFF_WGT;   // bf16 4096x1024 overlay (WgT dead in phase2)

__device__ __forceinline__ unsigned short f2bf(float f) {
  union { float f; uint32_t u; } v; v.f = f;
  uint32_t r = (v.u + 0x7FFFu + ((v.u >> 16) & 1u)) >> 16;
  return (unsigned short)r;
}
__device__ __forceinline__ float bfu2f(uint32_t u) {
  union { uint32_t u; float f; } v; v.u = u << 16; return v.f;
}
__device__ __forceinline__ bf16x8 as_bf16x8(ushort8 s) {
  union { ushort8 s; bf16x8 b; } u; u.s = s; return u.b;
}
__device__ __forceinline__ float silu(float g) { return g / (1.f + __expf(-g)); }

// async global->LDS, 16B/lane. Per-lane global addrs OK; LDS dest is
// wave-uniform base, lane l lands at base + l*16 (m104/m108).
__device__ __forceinline__ void glds16(const unsigned short* g, unsigned short* l) {
  __builtin_amdgcn_global_load_lds(
      (const __attribute__((address_space(1))) unsigned int*)g,
      (__attribute__((address_space(3))) unsigned int*)l, 16, 0, 0);
}

// Pipeline barriers WITHOUT the compiler's vmcnt(0) drain: wait only the
// oldest in-flight stage (6 glds/wave/stage, 3 stages in flight -> vmcnt(12)).
#define PIPE_WAIT() asm volatile("s_waitcnt vmcnt(12)\ns_barrier" ::: "memory")
#define PIPE_SYNC() asm volatile("s_waitcnt lgkmcnt(0)\ns_barrier" ::: "memory")

// -------------------------- init: zero expert counts -----------------------
__global__ void init_kernel(int* counts) {
  if (threadIdx.x < NEXP) counts[threadIdx.x] = 0;
}

// ------------- router (fp32, one wave/token) + fused x->bf16 write ---------
__global__ __launch_bounds__(64) void router_kernel(
    const float* __restrict__ x, const float* __restrict__ rw,
    int* counts, int* list, float* wt, int* tIdx,
    unsigned short* __restrict__ Xb) {
  const int t = blockIdx.x, l = threadIdx.x;
  float xv[16];
#pragma unroll
  for (int j = 0; j < 16; j++) xv[j] = x[t * HID + j * 64 + l];
#pragma unroll
  for (int j = 0; j < 16; j++) Xb[t * HID + j * 64 + l] = f2bf(xv[j]);
  float p[NEXP];
#pragma unroll
  for (int e = 0; e < NEXP; e++) {
    float s = 0.f;
#pragma unroll
    for (int j = 0; j < 16; j++) s += xv[j] * rw[e * HID + j * 64 + l];
#pragma unroll
    for (int off = 32; off > 0; off >>= 1) s += __shfl_xor(s, off);
    p[e] = s;
  }
  float mx = p[0];
#pragma unroll
  for (int e = 1; e < NEXP; e++) mx = fmaxf(mx, p[e]);
  int idx[TOPK]; float w4[TOPK]; float wsum = 0.f; unsigned used = 0u;
#pragma unroll
  for (int k = 0; k < TOPK; k++) {
    float bv = -1e30f; int bi = 0;
#pragma unroll
    for (int e = 0; e < NEXP; e++)
      if (!((used >> e) & 1u) && p[e] > bv) { bv = p[e]; bi = e; }
    used |= 1u << bi;
    idx[k] = bi;
    w4[k] = __expf(p[bi] - mx);
    wsum += w4[k];
  }
  const float inv = 1.f / wsum;  // softmax denom cancels under top-k renorm
  if (l < TOPK) {
    const int e = idx[l];
    const int pos = atomicAdd(&counts[e], 1);
    list[e * 1024 + pos] = t;
    wt[e * 1024 + pos]   = w4[l] * inv;
    tIdx[t * TOPK + l]   = (e << 10) | pos;
  }
}

// ---------------- one dispatch: all 5 weight transposes (fp32->bf16) -------
// 64x64 fp32 tiles; loads are float4 rows; stores pack 8 rows -> one 16B
// coalesced ushort8 store per lane (8 lanes = 128B contiguous per dst row).
__global__ __launch_bounds__(256) void transpose_all_kernel(
    const float* __restrict__ Wg, const float* __restrict__ Wu,
    const float* __restrict__ Wd, const float* __restrict__ Wsgu,
    const float* __restrict__ Wsd,
    unsigned short* __restrict__ WgT, unsigned short* __restrict__ WuT,
    unsigned short* __restrict__ WdT, unsigned short* __restrict__ WsguT,
    unsigned short* __restrict__ WsdT) {
  const int bid = blockIdx.x;
  const float* src; unsigned short* dst; int R, C, tx, ty; size_t bo;
  if (bid < 4096) {                    // Wg/Wu: [16][1024][512]
    const int which = bid >> 11, loc = bid & 2047;
    const int b = loc >> 7, t8 = loc & 127;
    src = which ? Wu : Wg; dst = which ? WuT : WgT;
    R = 1024; C = 512; bo = (size_t)b * R * C;
    tx = t8 & 7; ty = t8 >> 3;
  } else if (bid < 6144) {             // Wd: [16][512][1024]
    const int loc = bid - 4096, b = loc >> 7, t8 = loc & 127;
    src = Wd; dst = WdT; R = 512; C = 1024; bo = (size_t)b * R * C;
    tx = t8 & 15; ty = t8 >> 4;
  } else if (bid < 6656) {             // Wsgu: [1024][2048]
    const int loc = bid - 6144;
    src = Wsgu; dst = WsguT; R = 1024; C = 2048; bo = 0;
    tx = loc & 31; ty = loc >> 5;
  } else {                             // Wsd: [1024][1024]
    const int loc = bid - 6656;
    src = Wsd; dst = WsdT; R = 1024; C = 1024; bo = 0;
    tx = loc & 15; ty = loc >> 4;
  }
  __shared__ float tile[64][65];
  const int c0 = tx * 64, r0 = ty * 64, t = threadIdx.x;
  {
    const int r = t >> 4, c4 = (t & 15) * 4;
#pragma unroll
    for (int p = 0; p < 4; p++) {
      const int rr = p * 16 + r;
      const float4 v = *(const float4*)(src + bo + (size_t)(r0 + rr) * C + c0 + c4);
      tile[rr][c4 + 0] = v.x; tile[rr][c4 + 1] = v.y;
      tile[rr][c4 + 2] = v.z; tile[rr][c4 + 3] = v.w;
    }
  }
  __syncthreads();
#pragma unroll
  for (int half = 0; half < 2; half++) {
    const int c = half * 32 + (t >> 3), r8 = (t & 7) * 8;
    union { unsigned short u[8]; ushort8 v; } pk;
#pragma unroll
    for (int i = 0; i < 8; i++) pk.u[i] = f2bf(tile[r8 + i][c]);
    *(ushort8*)(dst + bo + (size_t)(c0 + c) * R + r0 + r8) = pk.v;
  }
}

// ---------------------------------------------------------------------------
// Phase 1: gate/up. Block 256 thr = 4 waves (2x2), tile 128m x 128n (G and U
// both), BK=32 (64B LDS rows). 3-buffer glds16 pipeline, asm barriers.
// Wave: 64m x 64n, 32 MFMA + 12 ds_read_b128 per step.
// ---------------------------------------------------------------------------
__global__ __launch_bounds__(256, 2) void phase1_kernel(
    const unsigned short* __restrict__ Xb,
    const unsigned short* __restrict__ WgT,   // [16][512][1024]
    const unsigned short* __restrict__ WuT,   // [16][512][1024]
    const unsigned short* __restrict__ WsguT, // [2048][1024]
    const int* __restrict__ counts, const int* __restrict__ list,
    const float* __restrict__ wt,
    unsigned short* __restrict__ Hr,          // [4096][512] compact
    unsigned short* __restrict__ Hs) {        // [1024][1024]
  const int z = blockIdx.z, x = blockIdx.x, y = blockIdx.y;
  const bool routed = (z < NEXP);
  int cnt = 0, base = 0;
  if (routed) {
    if (x >= 4) return;                       // routed: 4 x-tiles of 128 I-cols
    cnt = counts[z];
    if (y * 128 >= cnt) return;
#pragma unroll
    for (int i = 0; i < NEXP; i++) base += (i < z) ? counts[i] : 0;
  }
  __shared__ __align__(16) unsigned short sA[3][128 * 32];
  __shared__ __align__(16) unsigned short sB[3][256 * 32];
  const int tid = threadIdx.x, w = tid >> 6, l = tid & 63;
  const int wm = w >> 1, wn = w & 1, m0 = y * 128;

  // staging sources: stage = 2 A-glds + 4 B-glds per wave
  const unsigned short* aS[2];
#pragma unroll
  for (int ii = 0; ii < 2; ii++) {
    const int r = 32 * w + 16 * ii + (l >> 2);
    const unsigned short* row;
    if (routed) row = Xb + (size_t)list[z * 1024 + min(m0 + r, cnt - 1)] * HID;
    else        row = Xb + (size_t)(m0 + r) * HID;
    aS[ii] = row + (l & 3) * 8;
  }
  const unsigned short* bS[4];
#pragma unroll
  for (int ii = 0; ii < 4; ii++) {
    const int R = 64 * w + 16 * ii + (l >> 2);   // 0..255; 0-127 G, 128-255 U
    const int col = x * 128 + (R & 127);
    const unsigned short* row;
    if (routed) row = ((R >= 128) ? WuT : WgT) + ((size_t)z * MINTER + col) * HID;
    else        row = WsguT + (size_t)(((R >= 128) ? SINTER : 0) + col) * HID;
    bS[ii] = row + (l & 3) * 8;
  }

  int aOff[4], bOff[4];
#pragma unroll
  for (int i = 0; i < 4; i++) aOff[i] = (wm * 64 + 16 * i + (l & 15)) * 32 + (l >> 4) * 8;
#pragma unroll
  for (int j = 0; j < 4; j++) bOff[j] = (wn * 64 + 16 * j + (l & 15)) * 32 + (l >> 4) * 8;

  f32x4 accG[4][4], accU[4][4];
#pragma unroll
  for (int i = 0; i < 4; i++)
#pragma unroll
    for (int j = 0; j < 4; j++) {
      accG[i][j] = (f32x4){0.f, 0.f, 0.f, 0.f};
      accU[i][j] = (f32x4){0.f, 0.f, 0.f, 0.f};
    }

  auto stage = [&](int k0, int b) {
#pragma unroll
    for (int ii = 0; ii < 2; ii++) glds16(aS[ii] + k0, &sA[b][(32 * w + 16 * ii) * 32]);
#pragma unroll
    for (int ii = 0; ii < 4; ii++) glds16(bS[ii] + k0, &sB[b][(64 * w + 16 * ii) * 32]);
  };

  stage(0, 0); stage(32, 1); stage(64, 2);
  const int steps = HID / 32;   // 32
#pragma unroll 1
  for (int s = 0; s < steps; s++) {
    PIPE_WAIT();                            // stage s landed (all waves)
    const int cb = s % 3;
    const unsigned short* A = &sA[cb][0];
    const unsigned short* B = &sB[cb][0];
    bf16x8 af[4];
#pragma unroll
    for (int i = 0; i < 4; i++) af[i] = as_bf16x8(*(const ushort8*)(A + aOff[i]));
#pragma unroll
    for (int j = 0; j < 4; j++) {
      const bf16x8 gf = as_bf16x8(*(const ushort8*)(B + bOff[j]));
      const bf16x8 uf = as_bf16x8(*(const ushort8*)(B + 128 * 32 + bOff[j]));
#pragma unroll
      for (int i = 0; i < 4; i++) {
        accG[i][j] = __builtin_amdgcn_mfma_f32_16x16x32_bf16(af[i], gf, accG[i][j], 0, 0, 0);
        accU[i][j] = __builtin_amdgcn_mfma_f32_16x16x32_bf16(af[i], uf, accU[i][j], 0, 0, 0);
      }
    }
    PIPE_SYNC();                            // all waves done reading buf cb
    stage(((s + 3) & (steps - 1)) * 32, cb);  // tail wraps: harmless reload
  }

  // epilogue: C/D map col=lane&15, row=(lane>>4)*4+reg
#pragma unroll
  for (int i = 0; i < 4; i++)
#pragma unroll
    for (int r = 0; r < 4; r++) {
      const int row = wm * 64 + 16 * i + (l >> 4) * 4 + r;
      const int grow = m0 + row;
      if (routed) {
        if (grow < cnt) {
          const float wrow = wt[z * 1024 + grow];
#pragma unroll
          for (int j = 0; j < 4; j++) {
            const int col = x * 128 + wn * 64 + 16 * j + (l & 15);
            const float h = silu(accG[i][j][r]) * accU[i][j][r] * wrow;
            Hr[(size_t)(base + grow) * MINTER + col] = f2bf(h);
          }
        }
      } else {
#pragma unroll
        for (int j = 0; j < 4; j++) {
          const int col = x * 128 + wn * 64 + 16 * j + (l & 15);
          const float h = silu(accG[i][j][r]) * accU[i][j][r];
          Hs[(size_t)grow * SINTER + col] = f2bf(h);
        }
      }
    }
}

// ---------------------------------------------------------------------------
// Phase 2: down-proj. Block tile 128m x 256n, BK=32; wave 64m x 128n.
// Routed (z<16): K=512 -> bf16 Rout; shared (z==16): K=1024 -> fp32 out.
// Same 3-buffer pipeline.
// ---------------------------------------------------------------------------
__global__ __launch_bounds__(256, 2) void phase2_kernel(
    const unsigned short* __restrict__ Hr, const unsigned short* __restrict__ Hs,
    const unsigned short* __restrict__ WdT,  // [16][1024][512]
    const unsigned short* __restrict__ WsdT, // [1024][1024]
    const int* __restrict__ counts,
    unsigned short* __restrict__ Rout,       // [4096][1024] bf16 compact
    float* __restrict__ out) {               // [1024][1024]
  const int z = blockIdx.z, x = blockIdx.x, y = blockIdx.y;
  const bool routed = (z < NEXP);
  int cnt = 0, base = 0, kdim;
  if (routed) {
    cnt = counts[z];
    if (y * 128 >= cnt) return;
#pragma unroll
    for (int i = 0; i < NEXP; i++) base += (i < z) ? counts[i] : 0;
    kdim = MINTER;
  } else {
    kdim = SINTER;
  }
  __shared__ __align__(16) unsigned short sA[3][128 * 32];
  __shared__ __align__(16) unsigned short sB[3][256 * 32];
  const int tid = threadIdx.x, w = tid >> 6, l = tid & 63;
  const int wm = w >> 1, wn = w & 1, m0 = y * 128;

  const unsigned short* aS[2];
#pragma unroll
  for (int ii = 0; ii < 2; ii++) {
    const int r = 32 * w + 16 * ii + (l >> 2);
    const unsigned short* row;
    if (routed) row = Hr + (size_t)(base + min(m0 + r, cnt - 1)) * MINTER;
    else        row = Hs + (size_t)(m0 + r) * SINTER;
    aS[ii] = row + (l & 3) * 8;
  }
  const unsigned short* bS[4];
#pragma unroll
  for (int ii = 0; ii < 4; ii++) {
    const int R = 64 * w + 16 * ii + (l >> 2);   // 0..255 n-rows
    const int col = x * 256 + R;
    const unsigned short* row =
        routed ? (WdT + ((size_t)z * HID + col) * MINTER)
               : (WsdT + (size_t)col * SINTER);
    bS[ii] = row + (l & 3) * 8;
  }

  int aOff[4], bOff[8];
#pragma unroll
  for (int i = 0; i < 4; i++) aOff[i] = (wm * 64 + 16 * i + (l & 15)) * 32 + (l >> 4) * 8;
#pragma unroll
  for (int j = 0; j < 8; j++) bOff[j] = (wn * 128 + 16 * j + (l & 15)) * 32 + (l >> 4) * 8;

  f32x4 acc[4][8];
#pragma unroll
  for (int i = 0; i < 4; i++)
#pragma unroll
    for (int j = 0; j < 8; j++) acc[i][j] = (f32x4){0.f, 0.f, 0.f, 0.f};

  auto stage = [&](int k0, int b) {
#pragma unroll
    for (int ii = 0; ii < 2; ii++) glds16(aS[ii] + k0, &sA[b][(32 * w + 16 * ii) * 32]);
#pragma unroll
    for (int ii = 0; ii < 4; ii++) glds16(bS[ii] + k0, &sB[b][(64 * w + 16 * ii) * 32]);
  };

  stage(0, 0); stage(32, 1); stage(64, 2);
  const int steps = kdim / 32;   // 16 or 32 (power of 2)
#pragma unroll 1
  for (int s = 0; s < steps; s++) {
    PIPE_WAIT();
    const int cb = s % 3;
    const unsigned short* A = &sA[cb][0];
    const unsigned short* B = &sB[cb][0];
    bf16x8 af[4];
#pragma unroll
    for (int i = 0; i < 4; i++) af[i] = as_bf16x8(*(const ushort8*)(A + aOff[i]));
#pragma unroll
    for (int j = 0; j < 8; j++) {
      const bf16x8 bfv = as_bf16x8(*(const ushort8*)(B + bOff[j]));
#pragma unroll
      for (int i = 0; i < 4; i++)
        acc[i][j] = __builtin_amdgcn_mfma_f32_16x16x32_bf16(af[i], bfv, acc[i][j], 0, 0, 0);
    }
    PIPE_SYNC();
    stage(((s + 3) & (steps - 1)) * 32, cb);
  }

#pragma unroll
  for (int i = 0; i < 4; i++)
#pragma unroll
    for (int r = 0; r < 4; r++) {
      const int row = wm * 64 + 16 * i + (l >> 4) * 4 + r;
      const int grow = m0 + row;
      if (routed) {
        if (grow < cnt) {
#pragma unroll
          for (int j = 0; j < 8; j++) {
            const int col = x * 256 + wn * 128 + 16 * j + (l & 15);
            Rout[(size_t)(base + grow) * HID + col] = f2bf(acc[i][j][r]);
          }
        }
      } else {
#pragma unroll
        for (int j = 0; j < 8; j++) {
          const int col = x * 256 + wn * 128 + 16 * j + (l & 15);
          out[(size_t)grow * HID + col] = acc[i][j][r];
        }
      }
    }
}

// ------------- combine: out[t] += sum_k Rout[base[e_k]+pos_k] (bf16) -------
__global__ __launch_bounds__(256) void combine_kernel(
    const unsigned short* __restrict__ Rout, const int* __restrict__ counts,
    const int* __restrict__ tIdx, float* __restrict__ out) {
  __shared__ int sb[NEXP];
  if (threadIdx.x == 0) {
    int s = 0;
#pragma unroll
    for (int e = 0; e < NEXP; e++) { sb[e] = s; s += counts[e]; }
  }
  __syncthreads();
  const int t = blockIdx.x, c4 = threadIdx.x * 4;
  float4 o = *(const float4*)(out + (size_t)t * HID + c4);
#pragma unroll
  for (int k = 0; k < TOPK; k++) {
    const int v = tIdx[t * TOPK + k];
    const int row = sb[v >> 10] + (v & 1023);
    const uint2 rv = *(const uint2*)(Rout + (size_t)row * HID + c4);
    o.x += bfu2f(rv.x & 0xffffu); o.y += bfu2f(rv.x >> 16);
    o.z += bfu2f(rv.y & 0xffffu); o.w += bfu2f(rv.y >> 16);
  }
  *(float4*)(out + (size_t)t * HID + c4) = o;
}

// ---------------------------------------------------------------------------
extern "C" void kernel_launch(void* const* d_in, const int* in_sizes, int n_in,
                              void* d_out, int out_size, void* d_ws, size_t ws_size,
                              hipStream_t stream) {
  const float* x      = (const float*)d_in[0];
  const float* rw     = (const float*)d_in[1];
  const float* w_gate = (const float*)d_in[2];
  const float* w_up   = (const float*)d_in[3];
  const float* w_down = (const float*)d_in[4];
  const float* ws_gu  = (const float*)d_in[5];
  const float* ws_dn  = (const float*)d_in[6];
  float* out = (float*)d_out;
  char* ws = (char*)d_ws;

  int*   counts = (int*)  (ws + OFF_COUNTS);
  int*   list   = (int*)  (ws + OFF_LIST);
  float* wtbuf  = (float*)(ws + OFF_WT);
  int*   tIdx   = (int*)  (ws + OFF_TIDX);
  unsigned short* Xb    = (unsigned short*)(ws + OFF_XB);
  unsigned short* Hs    = (unsigned short*)(ws + OFF_HS);
  unsigned short* Hr    = (unsigned short*)(ws + OFF_HR);
  unsigned short* WgT   = (unsigned short*)(ws + OFF_WGT);
  unsigned short* WuT   = (unsigned short*)(ws + OFF_WUT);
  unsigned short* WdT   = (unsigned short*)(ws + OFF_WDT);
  unsigned short* WsguT = (unsigned short*)(ws + OFF_WSGUT);
  unsigned short* WsdT  = (unsigned short*)(ws + OFF_WSDT);
  unsigned short* Rout  = (unsigned short*)(ws + OFF_ROUT);

  init_kernel<<<1, 64, 0, stream>>>(counts);
  router_kernel<<<T_TOK, 64, 0, stream>>>(x, rw, counts, list, wtbuf, tIdx, Xb);
  transpose_all_kernel<<<6912, 256, 0, stream>>>(
      w_gate, w_up, w_down, ws_gu, ws_dn, WgT, WuT, WdT, WsguT, WsdT);
  phase1_kernel<<<dim3(8, 8, 17), 256, 0, stream>>>(
      Xb, WgT, WuT, WsguT, counts, list, wtbuf, Hr, Hs);
  phase2_kernel<<<dim3(4, 8, 17), 256, 0, stream>>>(
      Hr, Hs, WdT, WsdT, counts, Rout, out);
  combine_kernel<<<T_TOK, 256, 0, stream>>>(Rout, counts, tIdx, out);
  (void)in_sizes; (void)n_in; (void)out_size; (void)ws_size;
}

// Round 6
// 246.430 us; speedup vs baseline: 3.1248x; 1.1420x over previous
//
#include <hip/hip_runtime.h>
#include <stdint.h>

// ---------------------------------------------------------------------------
// BailingMoE block: T=1024, H=1024, E=16, top-4, I=512 routed, Is=1024 shared
// R6: occupancy-first GEMM phases. 64x128 block tiles (12 KB LDS, 32-reg acc)
// -> ~768/640 live blocks = 3-4 blocks/CU = 12-16 waves/CU (m97/m102 regime).
// Weights in k-panel layout [K/32][N][32] (G/U col-interleaved) so every
// glds16 stages a contiguous 1 KB. Hr/Hs panelized by phase1 epilogue.
// Simple 2-barrier K-loop; TLP across co-resident blocks hides the drain.
// ---------------------------------------------------------------------------

typedef __attribute__((ext_vector_type(8))) unsigned short ushort8;
typedef __attribute__((ext_vector_type(4))) float f32x4;
typedef __attribute__((ext_vector_type(8))) __bf16 bf16x8;

#define T_TOK 1024
#define HID   1024
#define NEXP  16
#define TOPK  4
#define MINTER 512
#define SINTER 1024

constexpr size_t WGU_E = 32 * 1024 * 32;   // per-expert gate/up panel elems
constexpr size_t WD_E  = 16 * 1024 * 32;   // per-expert down panel elems

constexpr size_t OFF_COUNTS = 0;                               // 16 ints
constexpr size_t OFF_LIST   = 1024;                            // 16*1024 ints
constexpr size_t OFF_WT     = OFF_LIST  + 65536;               // 16*1024 floats
constexpr size_t OFF_TIDX   = OFF_WT    + 65536;               // 4096 ints
constexpr size_t OFF_XB     = OFF_TIDX  + 65536;               // bf16 [1024][1024]
constexpr size_t OFF_HR     = OFF_XB    + 2097152;             // bf16 panels [16][4096][32]
constexpr size_t OFF_HS     = OFF_HR    + 4194304;             // bf16 panels [32][1024][32]
constexpr size_t OFF_WGU    = OFF_HS    + 2097152;             // bf16 [16] x WGU_E (33.5 MB)
constexpr size_t OFF_WD     = OFF_WGU   + 33554432;            // bf16 [16] x WD_E (16.8 MB)
constexpr size_t OFF_WSGU   = OFF_WD    + 16777216;            // bf16 [32][2048][32]
constexpr size_t OFF_WSD    = OFF_WSGU  + 4194304;             // bf16 [32][1024][32]
constexpr size_t OFF_ROUT   = OFF_WGU;   // bf16 [4096][1024] overlay (WGU dead in phase2)

__device__ __forceinline__ unsigned short f2bf(float f) {
  union { float f; uint32_t u; } v; v.f = f;
  uint32_t r = (v.u + 0x7FFFu + ((v.u >> 16) & 1u)) >> 16;
  return (unsigned short)r;
}
__device__ __forceinline__ float bfu2f(uint32_t u) {
  union { uint32_t u; float f; } v; v.u = u << 16; return v.f;
}
__device__ __forceinline__ bf16x8 as_bf16x8(ushort8 s) {
  union { ushort8 s; bf16x8 b; } u; u.s = s; return u.b;
}
__device__ __forceinline__ float silu(float g) { return g / (1.f + __expf(-g)); }

// async global->LDS, 16B/lane; LDS dest is wave-uniform base + lane*16.
__device__ __forceinline__ void glds16(const unsigned short* g, unsigned short* l) {
  __builtin_amdgcn_global_load_lds(
      (const __attribute__((address_space(1))) unsigned int*)g,
      (__attribute__((address_space(3))) unsigned int*)l, 16, 0, 0);
}

// -------------------------- init: zero expert counts -----------------------
__global__ void init_kernel(int* counts) {
  if (threadIdx.x < NEXP) counts[threadIdx.x] = 0;
}

// ------------- router (fp32, one wave/token) + fused x->bf16 write ---------
__global__ __launch_bounds__(64) void router_kernel(
    const float* __restrict__ x, const float* __restrict__ rw,
    int* counts, int* list, float* wt, int* tIdx,
    unsigned short* __restrict__ Xb) {
  const int t = blockIdx.x, l = threadIdx.x;
  float xv[16];
#pragma unroll
  for (int j = 0; j < 16; j++) xv[j] = x[t * HID + j * 64 + l];
#pragma unroll
  for (int j = 0; j < 16; j++) Xb[t * HID + j * 64 + l] = f2bf(xv[j]);
  float p[NEXP];
#pragma unroll
  for (int e = 0; e < NEXP; e++) {
    float s = 0.f;
#pragma unroll
    for (int j = 0; j < 16; j++) s += xv[j] * rw[e * HID + j * 64 + l];
#pragma unroll
    for (int off = 32; off > 0; off >>= 1) s += __shfl_xor(s, off);
    p[e] = s;
  }
  float mx = p[0];
#pragma unroll
  for (int e = 1; e < NEXP; e++) mx = fmaxf(mx, p[e]);
  int idx[TOPK]; float w4[TOPK]; float wsum = 0.f; unsigned used = 0u;
#pragma unroll
  for (int k = 0; k < TOPK; k++) {
    float bv = -1e30f; int bi = 0;
#pragma unroll
    for (int e = 0; e < NEXP; e++)
      if (!((used >> e) & 1u) && p[e] > bv) { bv = p[e]; bi = e; }
    used |= 1u << bi;
    idx[k] = bi;
    w4[k] = __expf(p[bi] - mx);
    wsum += w4[k];
  }
  const float inv = 1.f / wsum;  // softmax denom cancels under top-k renorm
  if (l < TOPK) {
    const int e = idx[l];
    const int pos = atomicAdd(&counts[e], 1);
    list[e * 1024 + pos] = t;
    wt[e * 1024 + pos]   = w4[l] * inv;
    tIdx[t * TOPK + l]   = (e << 10) | pos;
  }
}

// -------- pack_all: fp32 [K][N] weights -> bf16 k-panels [K/32][Nj][32] ----
// G/U interleave: packed j for G col c = (c>>6)*128 + (c&63); U: +64.
// Writes: each wave emits contiguous 1 KB runs (fully coalesced).
__global__ __launch_bounds__(256) void pack_all_kernel(
    const float* __restrict__ Wg, const float* __restrict__ Wu,
    const float* __restrict__ Wd, const float* __restrict__ Wsgu,
    const float* __restrict__ Wsd,
    unsigned short* __restrict__ WGUp, unsigned short* __restrict__ WDp,
    unsigned short* __restrict__ WSGUp, unsigned short* __restrict__ WSDp) {
  const int bid = blockIdx.x;
  const float* src; unsigned short* dst; int C, Nj, kp0, j0, r0, c0;
  if (bid < 2048) {                      // Wg: [16][1024][512]
    const int e = bid >> 7, loc = bid & 127, kt = loc >> 3, nt = loc & 7;
    src = Wg + (size_t)e * HID * MINTER; dst = WGUp + (size_t)e * WGU_E;
    C = MINTER; Nj = 1024; kp0 = 2 * kt; j0 = nt * 128; r0 = 64 * kt; c0 = 64 * nt;
  } else if (bid < 4096) {               // Wu
    const int e = (bid - 2048) >> 7, loc = bid & 127, kt = loc >> 3, nt = loc & 7;
    src = Wu + (size_t)e * HID * MINTER; dst = WGUp + (size_t)e * WGU_E;
    C = MINTER; Nj = 1024; kp0 = 2 * kt; j0 = nt * 128 + 64; r0 = 64 * kt; c0 = 64 * nt;
  } else if (bid < 6144) {               // Wd: [16][512][1024]
    const int e = (bid - 4096) >> 7, loc = bid & 127, kt = loc >> 4, nt = loc & 15;
    src = Wd + (size_t)e * MINTER * HID; dst = WDp + (size_t)e * WD_E;
    C = HID; Nj = 1024; kp0 = 2 * kt; j0 = 64 * nt; r0 = 64 * kt; c0 = 64 * nt;
  } else if (bid < 6656) {               // Wsgu: [1024][2048]
    const int loc = bid - 6144, kt = loc >> 5, nt = loc & 31;
    src = Wsgu; dst = WSGUp;
    C = 2048; Nj = 2048; kp0 = 2 * kt; r0 = 64 * kt; c0 = 64 * nt;
    j0 = (nt < 16) ? nt * 128 : (nt - 16) * 128 + 64;
  } else {                               // Wsd: [1024][1024]
    const int loc = bid - 6656, kt = loc >> 4, nt = loc & 15;
    src = Wsd; dst = WSDp;
    C = HID; Nj = 1024; kp0 = 2 * kt; j0 = 64 * nt; r0 = 64 * kt; c0 = 64 * nt;
  }
  __shared__ float tile[64][65];
  const int t = threadIdx.x;
  {
    const int r = t >> 4, c4 = (t & 15) * 4;
#pragma unroll
    for (int p = 0; p < 4; p++) {
      const int rr = p * 16 + r;
      const float4 v = *(const float4*)(src + (size_t)(r0 + rr) * C + c0 + c4);
      tile[rr][c4 + 0] = v.x; tile[rr][c4 + 1] = v.y;
      tile[rr][c4 + 2] = v.z; tile[rr][c4 + 3] = v.w;
    }
  }
  __syncthreads();
  {
    const int n = t >> 2, k8 = (t & 3) * 8;
#pragma unroll
    for (int h = 0; h < 2; h++) {
      const int k = 32 * h + k8;
      union { unsigned short u[8]; ushort8 v; } pk;
#pragma unroll
      for (int i = 0; i < 8; i++) pk.u[i] = f2bf(tile[k + i][n]);
      *(ushort8*)(dst + ((size_t)(kp0 + h) * Nj + j0 + n) * 32 + k8) = pk.v;
    }
  }
}

// ---------------------------------------------------------------------------
// Phase 1: gate/up. Block 64m x 128j (j: 0-63 G, 64-127 U), BK=32, 4 waves;
// wave = 16m x 128j, acc = 8 x f32x4. LDS 12 KB. 2-barrier K-loop.
// Chunk-XOR swizzle: lane l stages global chunk (l&3)^((l>>3)&3) of row l>>2;
// frag read uses chunk q^((row>>1)&3) -> 2-way bank alias (free, m136).
// ---------------------------------------------------------------------------
__global__ __launch_bounds__(256, 4) void phase1_kernel(
    const unsigned short* __restrict__ Xb,
    const unsigned short* __restrict__ WGUp,
    const unsigned short* __restrict__ WSGUp,
    const int* __restrict__ counts, const int* __restrict__ list,
    const float* __restrict__ wt,
    unsigned short* __restrict__ Hr,   // panels [16][4096][32]
    unsigned short* __restrict__ Hs) { // panels [32][1024][32]
  const int z = blockIdx.z, x = blockIdx.x, y = blockIdx.y;
  const bool routed = (z < NEXP);
  int cnt = 0, base = 0;
  if (routed) {
    if (x >= 8) return;                // routed Nj=1024 -> 8 x-tiles
    cnt = counts[z];
    if (y * 64 >= cnt) return;
#pragma unroll
    for (int i = 0; i < NEXP; i++) base += (i < z) ? counts[i] : 0;
  }
  __shared__ __align__(16) unsigned short sA[64 * 32];
  __shared__ __align__(16) unsigned short sB[128 * 32];
  const int tid = threadIdx.x, w = tid >> 6, l = tid & 63;
  const int m0 = y * 64;
  const int swz = ((l & 3) ^ ((l >> 3) & 3)) * 8;
  const size_t NjStep = (size_t)(routed ? 1024 : 2048) * 32;

  const unsigned short* aS;
  {
    const int r = m0 + 16 * w + (l >> 2);
    const unsigned short* row = routed
        ? Xb + (size_t)list[z * 1024 + min(r, cnt - 1)] * HID
        : Xb + (size_t)r * HID;
    aS = row + swz;
  }
  const unsigned short* pan = routed ? WGUp + (size_t)z * WGU_E : WSGUp;
  const unsigned short* bS[2];
#pragma unroll
  for (int ii = 0; ii < 2; ii++) {
    const int j = x * 128 + 32 * w + 16 * ii + (l >> 2);
    bS[ii] = pan + (size_t)j * 32 + swz;
  }
  const int rsw = ((l >> 4) ^ (((l & 15) >> 1) & 3)) * 8;
  const int aOff = (16 * w + (l & 15)) * 32 + rsw;
  int bOff[8];
#pragma unroll
  for (int jt = 0; jt < 8; jt++) bOff[jt] = (16 * jt + (l & 15)) * 32 + rsw;

  f32x4 acc[8];
#pragma unroll
  for (int jt = 0; jt < 8; jt++) acc[jt] = (f32x4){0.f, 0.f, 0.f, 0.f};

#pragma unroll 1
  for (int s = 0; s < HID / 32; s++) {
    __syncthreads();                         // protect buffer from readers
    glds16(aS + s * 32, sA + (16 * w) * 32);
    glds16(bS[0] + s * NjStep, sB + (32 * w) * 32);
    glds16(bS[1] + s * NjStep, sB + (32 * w + 16) * 32);
    __syncthreads();                         // drains vmcnt(0): stage visible
    const bf16x8 af = as_bf16x8(*(const ushort8*)(sA + aOff));
#pragma unroll
    for (int jt = 0; jt < 8; jt++) {
      const bf16x8 bf = as_bf16x8(*(const ushort8*)(sB + bOff[jt]));
      acc[jt] = __builtin_amdgcn_mfma_f32_16x16x32_bf16(af, bf, acc[jt], 0, 0, 0);
    }
  }

  // epilogue: D col=lane&15, row=(lane>>4)*4+reg. jt<4 = G, jt+4 = U.
  const int rl = (l >> 4) * 4;
#pragma unroll
  for (int jt = 0; jt < 4; jt++) {
    const int c = 64 * x + 16 * jt + (l & 15);   // original I / shared col
#pragma unroll
    for (int r = 0; r < 4; r++) {
      const int grow = m0 + 16 * w + rl + r;
      const float g = acc[jt][r], u = acc[jt + 4][r];
      if (routed) {
        if (grow < cnt) {
          const float h = silu(g) * u * wt[z * 1024 + grow];
          Hr[((size_t)(c >> 5) * 4096 + base + grow) * 32 + (c & 31)] = f2bf(h);
        }
      } else {
        const float h = silu(g) * u;
        Hs[((size_t)(c >> 5) * 1024 + grow) * 32 + (c & 31)] = f2bf(h);
      }
    }
  }
}

// ---------------------------------------------------------------------------
// Phase 2: down-proj. Block 64m x 128n, BK=32. A from Hr/Hs panels (contig),
// B from Wd/Wsd panels. Routed K=512 -> bf16 Rout rows; shared K=1024 -> out.
// ---------------------------------------------------------------------------
__global__ __launch_bounds__(256, 4) void phase2_kernel(
    const unsigned short* __restrict__ Hr, const unsigned short* __restrict__ Hs,
    const unsigned short* __restrict__ WDp, const unsigned short* __restrict__ WSDp,
    const int* __restrict__ counts,
    unsigned short* __restrict__ Rout,   // bf16 [4096][1024]
    float* __restrict__ out) {           // fp32 [1024][1024]
  const int z = blockIdx.z, x = blockIdx.x, y = blockIdx.y;
  const bool routed = (z < NEXP);
  int cnt = 0, base = 0, steps;
  if (routed) {
    cnt = counts[z];
    if (y * 64 >= cnt) return;
#pragma unroll
    for (int i = 0; i < NEXP; i++) base += (i < z) ? counts[i] : 0;
    steps = MINTER / 32;   // 16
  } else {
    steps = SINTER / 32;   // 32
  }
  __shared__ __align__(16) unsigned short sA[64 * 32];
  __shared__ __align__(16) unsigned short sB[128 * 32];
  const int tid = threadIdx.x, w = tid >> 6, l = tid & 63;
  const int m0 = y * 64;
  const int swz = ((l & 3) ^ ((l >> 3) & 3)) * 8;
  const size_t strideA = (size_t)(routed ? 4096 : 1024) * 32;
  const size_t strideB = (size_t)1024 * 32;

  const unsigned short* aS;
  {
    const int r = 16 * w + (l >> 2);
    const int R = routed ? (base + min(m0 + r, cnt - 1)) : (m0 + r);
    aS = (routed ? Hr : Hs) + (size_t)R * 32 + swz;
  }
  const unsigned short* pan = routed ? WDp + (size_t)z * WD_E : WSDp;
  const unsigned short* bS[2];
#pragma unroll
  for (int ii = 0; ii < 2; ii++) {
    const int j = x * 128 + 32 * w + 16 * ii + (l >> 2);
    bS[ii] = pan + (size_t)j * 32 + swz;
  }
  const int rsw = ((l >> 4) ^ (((l & 15) >> 1) & 3)) * 8;
  const int aOff = (16 * w + (l & 15)) * 32 + rsw;
  int bOff[8];
#pragma unroll
  for (int jt = 0; jt < 8; jt++) bOff[jt] = (16 * jt + (l & 15)) * 32 + rsw;

  f32x4 acc[8];
#pragma unroll
  for (int jt = 0; jt < 8; jt++) acc[jt] = (f32x4){0.f, 0.f, 0.f, 0.f};

#pragma unroll 1
  for (int s = 0; s < steps; s++) {
    __syncthreads();
    glds16(aS + s * strideA, sA + (16 * w) * 32);
    glds16(bS[0] + s * strideB, sB + (32 * w) * 32);
    glds16(bS[1] + s * strideB, sB + (32 * w + 16) * 32);
    __syncthreads();
    const bf16x8 af = as_bf16x8(*(const ushort8*)(sA + aOff));
#pragma unroll
    for (int jt = 0; jt < 8; jt++) {
      const bf16x8 bf = as_bf16x8(*(const ushort8*)(sB + bOff[jt]));
      acc[jt] = __builtin_amdgcn_mfma_f32_16x16x32_bf16(af, bf, acc[jt], 0, 0, 0);
    }
  }

  const int rl = (l >> 4) * 4;
#pragma unroll
  for (int jt = 0; jt < 8; jt++) {
    const int col = 128 * x + 16 * jt + (l & 15);
#pragma unroll
    for (int r = 0; r < 4; r++) {
      const int grow = m0 + 16 * w + rl + r;
      if (routed) {
        if (grow < cnt)
          Rout[(size_t)(base + grow) * HID + col] = f2bf(acc[jt][r]);
      } else {
        out[(size_t)grow * HID + col] = acc[jt][r];
      }
    }
  }
}

// ------------- combine: out[t] += sum_k Rout[base[e_k]+pos_k] (bf16) -------
__global__ __launch_bounds__(256) void combine_kernel(
    const unsigned short* __restrict__ Rout, const int* __restrict__ counts,
    const int* __restrict__ tIdx, float* __restrict__ out) {
  __shared__ int sb[NEXP];
  if (threadIdx.x == 0) {
    int s = 0;
#pragma unroll
    for (int e = 0; e < NEXP; e++) { sb[e] = s; s += counts[e]; }
  }
  __syncthreads();
  const int t = blockIdx.x, c4 = threadIdx.x * 4;
  float4 o = *(const float4*)(out + (size_t)t * HID + c4);
#pragma unroll
  for (int k = 0; k < TOPK; k++) {
    const int v = tIdx[t * TOPK + k];
    const int row = sb[v >> 10] + (v & 1023);
    const uint2 rv = *(const uint2*)(Rout + (size_t)row * HID + c4);
    o.x += bfu2f(rv.x & 0xffffu); o.y += bfu2f(rv.x >> 16);
    o.z += bfu2f(rv.y & 0xffffu); o.w += bfu2f(rv.y >> 16);
  }
  *(float4*)(out + (size_t)t * HID + c4) = o;
}

// ---------------------------------------------------------------------------
extern "C" void kernel_launch(void* const* d_in, const int* in_sizes, int n_in,
                              void* d_out, int out_size, void* d_ws, size_t ws_size,
                              hipStream_t stream) {
  const float* x      = (const float*)d_in[0];
  const float* rw     = (const float*)d_in[1];
  const float* w_gate = (const float*)d_in[2];
  const float* w_up   = (const float*)d_in[3];
  const float* w_down = (const float*)d_in[4];
  const float* ws_gu  = (const float*)d_in[5];
  const float* ws_dn  = (const float*)d_in[6];
  float* out = (float*)d_out;
  char* ws = (char*)d_ws;

  int*   counts = (int*)  (ws + OFF_COUNTS);
  int*   list   = (int*)  (ws + OFF_LIST);
  float* wtbuf  = (float*)(ws + OFF_WT);
  int*   tIdx   = (int*)  (ws + OFF_TIDX);
  unsigned short* Xb    = (unsigned short*)(ws + OFF_XB);
  unsigned short* Hr    = (unsigned short*)(ws + OFF_HR);
  unsigned short* Hs    = (unsigned short*)(ws + OFF_HS);
  unsigned short* WGUp  = (unsigned short*)(ws + OFF_WGU);
  unsigned short* WDp   = (unsigned short*)(ws + OFF_WD);
  unsigned short* WSGUp = (unsigned short*)(ws + OFF_WSGU);
  unsigned short* WSDp  = (unsigned short*)(ws + OFF_WSD);
  unsigned short* Rout  = (unsigned short*)(ws + OFF_ROUT);

  init_kernel<<<1, 64, 0, stream>>>(counts);
  router_kernel<<<T_TOK, 64, 0, stream>>>(x, rw, counts, list, wtbuf, tIdx, Xb);
  pack_all_kernel<<<6912, 256, 0, stream>>>(
      w_gate, w_up, w_down, ws_gu, ws_dn, WGUp, WDp, WSGUp, WSDp);
  phase1_kernel<<<dim3(16, 16, 17), 256, 0, stream>>>(
      Xb, WGUp, WSGUp, counts, list, wtbuf, Hr, Hs);
  phase2_kernel<<<dim3(8, 16, 17), 256, 0, stream>>>(
      Hr, Hs, WDp, WSDp, counts, Rout, out);
  combine_kernel<<<T_TOK, 256, 0, stream>>>(Rout, counts, tIdx, out);
  (void)in_sizes; (void)n_in; (void)out_size; (void)ws_size;
}

// Round 7
// 243.461 us; speedup vs baseline: 3.1629x; 1.0122x over previous
//
#include <hip/hip_runtime.h>
#include <stdint.h>

// ---------------------------------------------------------------------------
// BailingMoE block: T=1024, H=1024, E=16, top-4, I=512 routed, Is=1024 shared
// R7: R6 occupancy-first tiles + 3-stage glds16 pipeline with fine-grained
// s_waitcnt vmcnt(3) barriers (prefetch stays in flight across barriers).
// Block 128m x 64j, wave 64m x 32j (6 ds_read / 8 MFMA per step).
// G/U interleaved at 16-col granularity so silu is wave-local.
// ---------------------------------------------------------------------------

typedef __attribute__((ext_vector_type(8))) unsigned short ushort8;
typedef __attribute__((ext_vector_type(4))) float f32x4;
typedef __attribute__((ext_vector_type(8))) __bf16 bf16x8;

#define T_TOK 1024
#define HID   1024
#define NEXP  16
#define TOPK  4
#define MINTER 512
#define SINTER 1024

constexpr size_t WGU_E = 32 * 1024 * 32;   // per-expert gate/up panels
constexpr size_t WD_E  = 16 * 1024 * 32;   // per-expert down panels

constexpr size_t OFF_COUNTS = 0;
constexpr size_t OFF_LIST   = 1024;
constexpr size_t OFF_WT     = OFF_LIST  + 65536;
constexpr size_t OFF_TIDX   = OFF_WT    + 65536;
constexpr size_t OFF_XB     = OFF_TIDX  + 65536;               // bf16 [1024][1024]
constexpr size_t OFF_HR     = OFF_XB    + 2097152;             // bf16 [16][4096][32]
constexpr size_t OFF_HS     = OFF_HR    + 4194304;             // bf16 [32][1024][32]
constexpr size_t OFF_WGU    = OFF_HS    + 2097152;             // bf16 [16]xWGU_E
constexpr size_t OFF_WD     = OFF_WGU   + 33554432;            // bf16 [16]xWD_E
constexpr size_t OFF_WSGU   = OFF_WD    + 16777216;            // bf16 [32][2048][32]
constexpr size_t OFF_WSD    = OFF_WSGU  + 4194304;             // bf16 [32][1024][32]
constexpr size_t OFF_ROUT   = OFF_WGU;   // bf16 [4096][1024] overlay

__device__ __forceinline__ unsigned short f2bf(float f) {
  union { float f; uint32_t u; } v; v.f = f;
  uint32_t r = (v.u + 0x7FFFu + ((v.u >> 16) & 1u)) >> 16;
  return (unsigned short)r;
}
__device__ __forceinline__ float bfu2f(uint32_t u) {
  union { uint32_t u; float f; } v; v.u = u << 16; return v.f;
}
__device__ __forceinline__ bf16x8 as_bf16x8(ushort8 s) {
  union { ushort8 s; bf16x8 b; } u; u.s = s; return u.b;
}
__device__ __forceinline__ float silu(float g) { return g / (1.f + __expf(-g)); }

__device__ __forceinline__ void glds16(const unsigned short* g, unsigned short* l) {
  __builtin_amdgcn_global_load_lds(
      (const __attribute__((address_space(1))) unsigned int*)g,
      (__attribute__((address_space(3))) unsigned int*)l, 16, 0, 0);
}

// Barrier waiting only the OLDEST in-flight stage (3 glds/wave/stage; two
// newer stages = 6 loads stay in flight). lgkmcnt(0): wave's ds_reads of the
// previous compute are in registers before any buffer can be overwritten.
#define PIPE_BARRIER3() asm volatile("s_waitcnt vmcnt(3) lgkmcnt(0)\ns_barrier" ::: "memory")
#define PIPE_BARRIER0() asm volatile("s_waitcnt vmcnt(0) lgkmcnt(0)\ns_barrier" ::: "memory")

// -------------------------- init: zero expert counts -----------------------
__global__ void init_kernel(int* counts) {
  if (threadIdx.x < NEXP) counts[threadIdx.x] = 0;
}

// ------------- router (fp32, one wave/token) + fused x->bf16 write ---------
__global__ __launch_bounds__(64) void router_kernel(
    const float* __restrict__ x, const float* __restrict__ rw,
    int* counts, int* list, float* wt, int* tIdx,
    unsigned short* __restrict__ Xb) {
  const int t = blockIdx.x, l = threadIdx.x;
  float xv[16];
#pragma unroll
  for (int j = 0; j < 16; j++) xv[j] = x[t * HID + j * 64 + l];
#pragma unroll
  for (int j = 0; j < 16; j++) Xb[t * HID + j * 64 + l] = f2bf(xv[j]);
  float p[NEXP];
#pragma unroll
  for (int e = 0; e < NEXP; e++) {
    float s = 0.f;
#pragma unroll
    for (int j = 0; j < 16; j++) s += xv[j] * rw[e * HID + j * 64 + l];
#pragma unroll
    for (int off = 32; off > 0; off >>= 1) s += __shfl_xor(s, off);
    p[e] = s;
  }
  float mx = p[0];
#pragma unroll
  for (int e = 1; e < NEXP; e++) mx = fmaxf(mx, p[e]);
  int idx[TOPK]; float w4[TOPK]; float wsum = 0.f; unsigned used = 0u;
#pragma unroll
  for (int k = 0; k < TOPK; k++) {
    float bv = -1e30f; int bi = 0;
#pragma unroll
    for (int e = 0; e < NEXP; e++)
      if (!((used >> e) & 1u) && p[e] > bv) { bv = p[e]; bi = e; }
    used |= 1u << bi;
    idx[k] = bi;
    w4[k] = __expf(p[bi] - mx);
    wsum += w4[k];
  }
  const float inv = 1.f / wsum;
  if (l < TOPK) {
    const int e = idx[l];
    const int pos = atomicAdd(&counts[e], 1);
    list[e * 1024 + pos] = t;
    wt[e * 1024 + pos]   = w4[l] * inv;
    tIdx[t * TOPK + l]   = (e << 10) | pos;
  }
}

// -------- pack_all: fp32 [K][N] weights -> bf16 k-panels [K/32][Nj][32] ----
// Interleaved (gate/up): packed j for col c = 32*(c>>4)+(c&15) (+16 for up).
__global__ __launch_bounds__(256) void pack_all_kernel(
    const float* __restrict__ Wg, const float* __restrict__ Wu,
    const float* __restrict__ Wd, const float* __restrict__ Wsgu,
    const float* __restrict__ Wsd,
    unsigned short* __restrict__ WGUp, unsigned short* __restrict__ WDp,
    unsigned short* __restrict__ WSGUp, unsigned short* __restrict__ WSDp) {
  const int bid = blockIdx.x;
  const float* src; unsigned short* dst; int C, Nj, kp0, r0, c0, jbase, ilv;
  if (bid < 2048) {                      // Wg: [16][1024][512]
    const int e = bid >> 7, loc = bid & 127, kt = loc >> 3, nt = loc & 7;
    src = Wg + (size_t)e * HID * MINTER; dst = WGUp + (size_t)e * WGU_E;
    C = MINTER; Nj = 1024; kp0 = 2 * kt; r0 = 64 * kt; c0 = 64 * nt;
    jbase = 128 * nt; ilv = 1;
  } else if (bid < 4096) {               // Wu
    const int e = (bid - 2048) >> 7, loc = bid & 127, kt = loc >> 3, nt = loc & 7;
    src = Wu + (size_t)e * HID * MINTER; dst = WGUp + (size_t)e * WGU_E;
    C = MINTER; Nj = 1024; kp0 = 2 * kt; r0 = 64 * kt; c0 = 64 * nt;
    jbase = 128 * nt + 16; ilv = 1;
  } else if (bid < 6144) {               // Wd: [16][512][1024]
    const int e = (bid - 4096) >> 7, loc = bid & 127, kt = loc >> 4, nt = loc & 15;
    src = Wd + (size_t)e * MINTER * HID; dst = WDp + (size_t)e * WD_E;
    C = HID; Nj = 1024; kp0 = 2 * kt; r0 = 64 * kt; c0 = 64 * nt;
    jbase = 64 * nt; ilv = 0;
  } else if (bid < 6656) {               // Wsgu: [1024][2048]
    const int loc = bid - 6144, kt = loc >> 5, nt = loc & 31;
    src = Wsgu; dst = WSGUp;
    C = 2048; Nj = 2048; kp0 = 2 * kt; r0 = 64 * kt; c0 = 64 * nt;
    const int isU = (nt >= 16), ntc = nt & 15;
    jbase = 128 * ntc + 16 * isU; ilv = 1;
  } else {                               // Wsd: [1024][1024]
    const int loc = bid - 6656, kt = loc >> 4, nt = loc & 15;
    src = Wsd; dst = WSDp;
    C = HID; Nj = 1024; kp0 = 2 * kt; r0 = 64 * kt; c0 = 64 * nt;
    jbase = 64 * nt; ilv = 0;
  }
  __shared__ float tile[64][65];
  const int t = threadIdx.x;
  {
    const int r = t >> 4, c4 = (t & 15) * 4;
#pragma unroll
    for (int p = 0; p < 4; p++) {
      const int rr = p * 16 + r;
      const float4 v = *(const float4*)(src + (size_t)(r0 + rr) * C + c0 + c4);
      tile[rr][c4 + 0] = v.x; tile[rr][c4 + 1] = v.y;
      tile[rr][c4 + 2] = v.z; tile[rr][c4 + 3] = v.w;
    }
  }
  __syncthreads();
  {
    const int n = t >> 2, k8 = (t & 3) * 8;
    const int j = jbase + (ilv ? (32 * (n >> 4) + (n & 15)) : n);
#pragma unroll
    for (int h = 0; h < 2; h++) {
      const int k = 32 * h + k8;
      union { unsigned short u[8]; ushort8 v; } pk;
#pragma unroll
      for (int i = 0; i < 8; i++) pk.u[i] = f2bf(tile[k + i][n]);
      *(ushort8*)(dst + ((size_t)(kp0 + h) * Nj + j) * 32 + k8) = pk.v;
    }
  }
}

// ---------------------------------------------------------------------------
// Phase 1: gate/up. Block 128m x 64j (j interleaved: 32j per wave = 16G+16U),
// BK=32, 4 waves (wm=w>>1 m-half, wn=w&1 j-half). Wave: 4 A-frags, 2 B-frags,
// 8 MFMA per step. 3-stage pipeline, vmcnt(3) barriers. LDS 36 KB.
// ---------------------------------------------------------------------------
__global__ __launch_bounds__(256, 4) void phase1_kernel(
    const unsigned short* __restrict__ Xb,
    const unsigned short* __restrict__ WGUp,
    const unsigned short* __restrict__ WSGUp,
    const int* __restrict__ counts, const int* __restrict__ list,
    const float* __restrict__ wt,
    unsigned short* __restrict__ Hr,   // [16][4096][32]
    unsigned short* __restrict__ Hs) { // [32][1024][32]
  const int z = blockIdx.z, x = blockIdx.x, y = blockIdx.y;
  const bool routed = (z < NEXP);
  int cnt = 0, base = 0;
  if (routed) {
    if (x >= 16) return;               // routed Nj=1024 -> 16 x-tiles of 64
    cnt = counts[z];
    if (y * 128 >= cnt) return;
#pragma unroll
    for (int i = 0; i < NEXP; i++) base += (i < z) ? counts[i] : 0;
  }
  __shared__ __align__(16) unsigned short sA[3][128 * 32];
  __shared__ __align__(16) unsigned short sB[3][64 * 32];
  const int tid = threadIdx.x, w = tid >> 6, l = tid & 63;
  const int wm = w >> 1, wn = w & 1, m0 = y * 128;
  const int swz = ((l & 3) ^ ((l >> 3) & 3)) * 8;
  const int Nj = routed ? 1024 : 2048;

  // A staging: wave w covers sA rows [32w,32w+32) as 2 glds of 16 rows
  const unsigned short* aS[2];
#pragma unroll
  for (int ii = 0; ii < 2; ii++) {
    const int r = 32 * w + 16 * ii + (l >> 2);
    const unsigned short* row = routed
        ? Xb + (size_t)list[z * 1024 + min(m0 + r, cnt - 1)] * HID
        : Xb + (size_t)(m0 + r) * HID;
    aS[ii] = row + swz;
  }
  // B staging: wave w covers sB rows [16w,16w+16) as 1 glds
  const unsigned short* pan = routed ? WGUp + (size_t)z * WGU_E : WSGUp;
  const unsigned short* bS = pan + ((size_t)(x * 64 + 16 * w + (l >> 2))) * 32 + swz;
  const size_t bStep = (size_t)Nj * 32;

  const int rsw = ((l >> 4) ^ (((l & 15) >> 1) & 3)) * 8;
  int aOff[4], bOff[2];
#pragma unroll
  for (int i = 0; i < 4; i++) aOff[i] = (wm * 64 + 16 * i + (l & 15)) * 32 + rsw;
#pragma unroll
  for (int jt = 0; jt < 2; jt++) bOff[jt] = (wn * 32 + 16 * jt + (l & 15)) * 32 + rsw;

  f32x4 acc[4][2];
#pragma unroll
  for (int i = 0; i < 4; i++)
#pragma unroll
    for (int jt = 0; jt < 2; jt++) acc[i][jt] = (f32x4){0.f, 0.f, 0.f, 0.f};

  auto stage = [&](int s, int b) {
    glds16(aS[0] + s * 32, &sA[b][(32 * w) * 32]);
    glds16(aS[1] + s * 32, &sA[b][(32 * w + 16) * 32]);
    glds16(bS + s * bStep, &sB[b][(16 * w) * 32]);
  };

  const int steps = HID / 32;   // 32
  stage(0, 0); stage(1, 1);
#pragma unroll 1
  for (int s = 0; s < steps; s++) {
    const int cb = s % 3;
    if (s + 2 < steps) { PIPE_BARRIER3(); stage(s + 2, (s + 2) % 3); }
    else if (s + 1 < steps) { PIPE_BARRIER3(); }
    else { PIPE_BARRIER0(); }
    const unsigned short* A = &sA[cb][0];
    const unsigned short* B = &sB[cb][0];
    bf16x8 af[4], bfr[2];
#pragma unroll
    for (int i = 0; i < 4; i++) af[i] = as_bf16x8(*(const ushort8*)(A + aOff[i]));
#pragma unroll
    for (int jt = 0; jt < 2; jt++) bfr[jt] = as_bf16x8(*(const ushort8*)(B + bOff[jt]));
#pragma unroll
    for (int jt = 0; jt < 2; jt++)
#pragma unroll
      for (int i = 0; i < 4; i++)
        acc[i][jt] = __builtin_amdgcn_mfma_f32_16x16x32_bf16(af[i], bfr[jt], acc[i][jt], 0, 0, 0);
  }

  // epilogue: D col=lane&15, row=(lane>>4)*4+reg; jt=0 -> G, jt=1 -> U.
  // I-col c = 32x + 16wn + (lane&15); panel = x, in-panel col = 16wn+(lane&15).
  const int rl = (l >> 4) * 4, pc = 16 * wn + (l & 15);
#pragma unroll
  for (int i = 0; i < 4; i++)
#pragma unroll
    for (int r = 0; r < 4; r++) {
      const int grow = m0 + wm * 64 + 16 * i + rl + r;
      const float g = acc[i][0][r], u = acc[i][1][r];
      if (routed) {
        if (grow < cnt) {
          const float h = silu(g) * u * wt[z * 1024 + grow];
          Hr[((size_t)x * 4096 + base + grow) * 32 + pc] = f2bf(h);
        }
      } else {
        const float h = silu(g) * u;
        Hs[((size_t)x * 1024 + grow) * 32 + pc] = f2bf(h);
      }
    }
}

// ---------------------------------------------------------------------------
// Phase 2: down-proj. Block 128m x 64n, wave 64m x 32n, BK=32; same pipeline.
// Routed (z<16): K=512 -> bf16 Rout; shared (z==16): K=1024 -> fp32 out.
// ---------------------------------------------------------------------------
__global__ __launch_bounds__(256, 4) void phase2_kernel(
    const unsigned short* __restrict__ Hr, const unsigned short* __restrict__ Hs,
    const unsigned short* __restrict__ WDp, const unsigned short* __restrict__ WSDp,
    const int* __restrict__ counts,
    unsigned short* __restrict__ Rout,   // bf16 [4096][1024]
    float* __restrict__ out) {           // fp32 [1024][1024]
  const int z = blockIdx.z, x = blockIdx.x, y = blockIdx.y;
  const bool routed = (z < NEXP);
  int cnt = 0, base = 0, steps;
  if (routed) {
    cnt = counts[z];
    if (y * 128 >= cnt) return;
#pragma unroll
    for (int i = 0; i < NEXP; i++) base += (i < z) ? counts[i] : 0;
    steps = MINTER / 32;   // 16
  } else {
    steps = SINTER / 32;   // 32
  }
  __shared__ __align__(16) unsigned short sA[3][128 * 32];
  __shared__ __align__(16) unsigned short sB[3][64 * 32];
  const int tid = threadIdx.x, w = tid >> 6, l = tid & 63;
  const int wm = w >> 1, wn = w & 1, m0 = y * 128;
  const int swz = ((l & 3) ^ ((l >> 3) & 3)) * 8;
  const size_t aStep = (size_t)(routed ? 4096 : 1024) * 32;

  const unsigned short* aS[2];
#pragma unroll
  for (int ii = 0; ii < 2; ii++) {
    const int r = 32 * w + 16 * ii + (l >> 2);
    const int R = routed ? (base + min(m0 + r, cnt - 1)) : (m0 + r);
    aS[ii] = (routed ? Hr : Hs) + (size_t)R * 32 + swz;
  }
  const unsigned short* pan = routed ? WDp + (size_t)z * WD_E : WSDp;
  const unsigned short* bS = pan + ((size_t)(x * 64 + 16 * w + (l >> 2))) * 32 + swz;
  const size_t bStep = (size_t)1024 * 32;

  const int rsw = ((l >> 4) ^ (((l & 15) >> 1) & 3)) * 8;
  int aOff[4], bOff[2];
#pragma unroll
  for (int i = 0; i < 4; i++) aOff[i] = (wm * 64 + 16 * i + (l & 15)) * 32 + rsw;
#pragma unroll
  for (int jt = 0; jt < 2; jt++) bOff[jt] = (wn * 32 + 16 * jt + (l & 15)) * 32 + rsw;

  f32x4 acc[4][2];
#pragma unroll
  for (int i = 0; i < 4; i++)
#pragma unroll
    for (int jt = 0; jt < 2; jt++) acc[i][jt] = (f32x4){0.f, 0.f, 0.f, 0.f};

  auto stage = [&](int s, int b) {
    glds16(aS[0] + s * aStep, &sA[b][(32 * w) * 32]);
    glds16(aS[1] + s * aStep, &sA[b][(32 * w + 16) * 32]);
    glds16(bS + s * bStep, &sB[b][(16 * w) * 32]);
  };

  stage(0, 0); stage(1, 1);
#pragma unroll 1
  for (int s = 0; s < steps; s++) {
    const int cb = s % 3;
    if (s + 2 < steps) { PIPE_BARRIER3(); stage(s + 2, (s + 2) % 3); }
    else if (s + 1 < steps) { PIPE_BARRIER3(); }
    else { PIPE_BARRIER0(); }
    const unsigned short* A = &sA[cb][0];
    const unsigned short* B = &sB[cb][0];
    bf16x8 af[4], bfr[2];
#pragma unroll
    for (int i = 0; i < 4; i++) af[i] = as_bf16x8(*(const ushort8*)(A + aOff[i]));
#pragma unroll
    for (int jt = 0; jt < 2; jt++) bfr[jt] = as_bf16x8(*(const ushort8*)(B + bOff[jt]));
#pragma unroll
    for (int jt = 0; jt < 2; jt++)
#pragma unroll
      for (int i = 0; i < 4; i++)
        acc[i][jt] = __builtin_amdgcn_mfma_f32_16x16x32_bf16(af[i], bfr[jt], acc[i][jt], 0, 0, 0);
  }

  const int rl = (l >> 4) * 4;
#pragma unroll
  for (int i = 0; i < 4; i++)
#pragma unroll
    for (int r = 0; r < 4; r++) {
      const int grow = m0 + wm * 64 + 16 * i + rl + r;
#pragma unroll
      for (int jt = 0; jt < 2; jt++) {
        const int col = 64 * x + 32 * wn + 16 * jt + (l & 15);
        if (routed) {
          if (grow < cnt)
            Rout[(size_t)(base + grow) * HID + col] = f2bf(acc[i][jt][r]);
        } else {
          out[(size_t)grow * HID + col] = acc[i][jt][r];
        }
      }
    }
}

// ------------- combine: out[t] += sum_k Rout[base[e_k]+pos_k] (bf16) -------
__global__ __launch_bounds__(256) void combine_kernel(
    const unsigned short* __restrict__ Rout, const int* __restrict__ counts,
    const int* __restrict__ tIdx, float* __restrict__ out) {
  __shared__ int sb[NEXP];
  if (threadIdx.x == 0) {
    int s = 0;
#pragma unroll
    for (int e = 0; e < NEXP; e++) { sb[e] = s; s += counts[e]; }
  }
  __syncthreads();
  const int t = blockIdx.x, c4 = threadIdx.x * 4;
  float4 o = *(const float4*)(out + (size_t)t * HID + c4);
#pragma unroll
  for (int k = 0; k < TOPK; k++) {
    const int v = tIdx[t * TOPK + k];
    const int row = sb[v >> 10] + (v & 1023);
    const uint2 rv = *(const uint2*)(Rout + (size_t)row * HID + c4);
    o.x += bfu2f(rv.x & 0xffffu); o.y += bfu2f(rv.x >> 16);
    o.z += bfu2f(rv.y & 0xffffu); o.w += bfu2f(rv.y >> 16);
  }
  *(float4*)(out + (size_t)t * HID + c4) = o;
}

// ---------------------------------------------------------------------------
extern "C" void kernel_launch(void* const* d_in, const int* in_sizes, int n_in,
                              void* d_out, int out_size, void* d_ws, size_t ws_size,
                              hipStream_t stream) {
  const float* x      = (const float*)d_in[0];
  const float* rw     = (const float*)d_in[1];
  const float* w_gate = (const float*)d_in[2];
  const float* w_up   = (const float*)d_in[3];
  const float* w_down = (const float*)d_in[4];
  const float* ws_gu  = (const float*)d_in[5];
  const float* ws_dn  = (const float*)d_in[6];
  float* out = (float*)d_out;
  char* ws = (char*)d_ws;

  int*   counts = (int*)  (ws + OFF_COUNTS);
  int*   list   = (int*)  (ws + OFF_LIST);
  float* wtbuf  = (float*)(ws + OFF_WT);
  int*   tIdx   = (int*)  (ws + OFF_TIDX);
  unsigned short* Xb    = (unsigned short*)(ws + OFF_XB);
  unsigned short* Hr    = (unsigned short*)(ws + OFF_HR);
  unsigned short* Hs    = (unsigned short*)(ws + OFF_HS);
  unsigned short* WGUp  = (unsigned short*)(ws + OFF_WGU);
  unsigned short* WDp   = (unsigned short*)(ws + OFF_WD);
  unsigned short* WSGUp = (unsigned short*)(ws + OFF_WSGU);
  unsigned short* WSDp  = (unsigned short*)(ws + OFF_WSD);
  unsigned short* Rout  = (unsigned short*)(ws + OFF_ROUT);

  init_kernel<<<1, 64, 0, stream>>>(counts);
  router_kernel<<<T_TOK, 64, 0, stream>>>(x, rw, counts, list, wtbuf, tIdx, Xb);
  pack_all_kernel<<<6912, 256, 0, stream>>>(
      w_gate, w_up, w_down, ws_gu, ws_dn, WGUp, WDp, WSGUp, WSDp);
  phase1_kernel<<<dim3(32, 8, 17), 256, 0, stream>>>(
      Xb, WGUp, WSGUp, counts, list, wtbuf, Hr, Hs);
  phase2_kernel<<<dim3(16, 8, 17), 256, 0, stream>>>(
      Hr, Hs, WDp, WSDp, counts, Rout, out);
  combine_kernel<<<T_TOK, 256, 0, stream>>>(Rout, counts, tIdx, out);
  (void)in_sizes; (void)n_in; (void)out_size; (void)ws_size;
}